// Round 1
// baseline (132736.047 us; speedup 1.0000x reference)
//
#include <hip/hip_runtime.h>
#include <hip/hip_bf16.h>
#include <math.h>

// Problem constants (from reference)
#define NA   4096      // num agents / edges
#define FDIM 512
#define SDIM 6
#define HID  20
#define GDIM 2048      // 4*FDIM (LSTM gate width)
#define LWG  32        // workgroups in the persistent LSTM kernel

__device__ __forceinline__ float sigf(float x) { return 1.0f / (1.0f + __expf(-x)); }
__device__ __forceinline__ float tanh_fast(float x) {
    // 1 - 2/(exp(2x)+1): exact saturation at +/-1, no inf/inf NaN
    float e = __expf(2.0f * x);
    return 1.0f - 2.0f / (e + 1.0f);
}

__device__ __forceinline__ void atomicMaxF(float* addr, float v) {
    if (v >= 0.0f) atomicMax((int*)addr, __float_as_int(v));
    else           atomicMin((unsigned int*)addr, __float_as_uint(v));
}

// ---------------------------------------------------------------------------
// phi MLP, fused per edge: msg = [xin[src] | states[src]-states[dst]] (518)
// h = relu(msg@w0+b0); h = relu(h@w1+b1); phi = h@w2+b2
// ---------------------------------------------------------------------------
__global__ void phi_fused(const float* __restrict__ xin, const float* __restrict__ states,
                          const int* __restrict__ src, const int* __restrict__ dst,
                          const float* __restrict__ w0, const float* __restrict__ b0,
                          const float* __restrict__ w1, const float* __restrict__ b1,
                          const float* __restrict__ w2, const float* __restrict__ b2,
                          float* __restrict__ phi)
{
    int e = blockIdx.x, tid = threadIdx.x;
    __shared__ float msgv[FDIM + SDIM];
    __shared__ float hb1[HID];
    __shared__ float hb2[HID];
    int s = src[e], d = dst[e];
    for (int i = tid; i < FDIM; i += 64) msgv[i] = xin[(size_t)s * FDIM + i];
    if (tid < SDIM) msgv[FDIM + tid] = states[s * SDIM + tid] - states[d * SDIM + tid];
    __syncthreads();
    if (tid < HID) {
        float acc = b0[tid];
        for (int k = 0; k < FDIM + SDIM; k++) acc += msgv[k] * w0[k * HID + tid];
        hb1[tid] = fmaxf(acc, 0.0f);
    }
    __syncthreads();
    if (tid < HID) {
        float acc = b1[tid];
        for (int k = 0; k < HID; k++) acc += hb1[k] * w1[k * HID + tid];
        hb2[tid] = fmaxf(acc, 0.0f);
    }
    __syncthreads();
    for (int c = tid; c < FDIM; c += 64) {
        float acc = b2[c];
        for (int k = 0; k < HID; k++) acc += hb2[k] * w2[k * FDIM + c];
        phi[(size_t)e * FDIM + c] = acc;
    }
}

// ---------------------------------------------------------------------------
// fp32 tiled GEMM: C[M,N] = A[M,K] @ B[K,N] + bias[N]
// A is split: col k < splitA reads A1 (lda1), else A2 (lda2) at col k-splitA.
// 64x64 tile, 256 threads, 4x4 microtile, K-tile 16.
// ---------------------------------------------------------------------------
__global__ void __launch_bounds__(256)
gemm64(const float* __restrict__ A1, int lda1,
       const float* __restrict__ A2, int lda2, int splitA,
       const float* __restrict__ B, const float* __restrict__ bias,
       float* __restrict__ C, int M, int N, int K)
{
    __shared__ float a_lds[16][64];
    __shared__ float b_lds[16][64];
    int tid = threadIdx.x;
    int m0 = blockIdx.y * 64, n0 = blockIdx.x * 64;
    int tr = tid >> 2, tc4 = (tid & 3) * 4;       // A-tile loader: row, k*4
    int bry = tid >> 4, bc4 = (tid & 15) * 4;     // B-tile loader
    int ty = tid >> 4, tx = tid & 15;             // compute coords
    float acc[4][4] = {};

    for (int kt = 0; kt < K; kt += 16) {
        int ak = kt + tc4;
        const float* arow;
        int acol;
        if (ak < splitA) { arow = A1 + (size_t)(m0 + tr) * lda1; acol = ak; }
        else             { arow = A2 + (size_t)(m0 + tr) * lda2; acol = ak - splitA; }
        float4 av = *(const float4*)(arow + acol);
        a_lds[tc4 + 0][tr] = av.x;
        a_lds[tc4 + 1][tr] = av.y;
        a_lds[tc4 + 2][tr] = av.z;
        a_lds[tc4 + 3][tr] = av.w;
        float4 bv = *(const float4*)(B + (size_t)(kt + bry) * N + n0 + bc4);
        *(float4*)&b_lds[bry][bc4] = bv;
        __syncthreads();
#pragma unroll
        for (int kk = 0; kk < 16; kk++) {
            float4 a = *(const float4*)&a_lds[kk][ty * 4];
            float4 b = *(const float4*)&b_lds[kk][tx * 4];
            acc[0][0] += a.x * b.x; acc[0][1] += a.x * b.y; acc[0][2] += a.x * b.z; acc[0][3] += a.x * b.w;
            acc[1][0] += a.y * b.x; acc[1][1] += a.y * b.y; acc[1][2] += a.y * b.z; acc[1][3] += a.y * b.w;
            acc[2][0] += a.z * b.x; acc[2][1] += a.z * b.y; acc[2][2] += a.z * b.z; acc[2][3] += a.z * b.w;
            acc[3][0] += a.w * b.x; acc[3][1] += a.w * b.y; acc[3][2] += a.w * b.z; acc[3][3] += a.w * b.w;
        }
        __syncthreads();
    }
    float4 bb = *(const float4*)(bias + n0 + tx * 4);
#pragma unroll
    for (int i = 0; i < 4; i++) {
        int row = m0 + ty * 4 + i;
        float4 o;
        o.x = acc[i][0] + bb.x; o.y = acc[i][1] + bb.y; o.z = acc[i][2] + bb.z; o.w = acc[i][3] + bb.w;
        *(float4*)&C[(size_t)row * N + n0 + tx * 4] = o;
    }
}

// ---------------------------------------------------------------------------
// attention (generic segment softmax; with dst=arange it is singleton/exact)
// ---------------------------------------------------------------------------
__global__ void att_init(float* __restrict__ m, float* __restrict__ ssum)
{
    int i = blockIdx.x * blockDim.x + threadIdx.x;
    if (i < NA) { m[i] = -INFINITY; ssum[i] = 0.0f; }
}

__global__ void att_logits(const float* __restrict__ q, const float* __restrict__ k,
                           const int* __restrict__ src, const int* __restrict__ dst,
                           float* __restrict__ logits, float* __restrict__ m)
{
    int e = blockIdx.x, tid = threadIdx.x;
    int s = src[e], d = dst[e];
    const float4* qr = (const float4*)(q + (size_t)d * FDIM);
    const float4* kr = (const float4*)(k + (size_t)s * FDIM);
    float acc = 0.0f;
    for (int i = tid; i < FDIM / 4; i += 64) {
        float4 a = qr[i], b = kr[i];
        acc += a.x * b.x + a.y * b.y + a.z * b.z + a.w * b.w;
    }
    for (int off = 32; off; off >>= 1) acc += __shfl_down(acc, off);
    if (tid == 0) {
        float v = acc * 0.04419417382415922f;   // 1/sqrt(512)
        logits[e] = v;
        atomicMaxF(&m[d], v);
    }
}

__global__ void att_expsum(const float* __restrict__ logits, const float* __restrict__ m,
                           const int* __restrict__ dst,
                           float* __restrict__ ebuf, float* __restrict__ ssum)
{
    int e = blockIdx.x * blockDim.x + threadIdx.x;
    if (e < NA) {
        float v = __expf(logits[e] - m[dst[e]]);
        ebuf[e] = v;
        atomicAdd(&ssum[dst[e]], v);
    }
}

__global__ void att_scatter(const float* __restrict__ v, const int* __restrict__ src,
                            const int* __restrict__ dst, const float* __restrict__ ebuf,
                            const float* __restrict__ ssum, float* __restrict__ aggr)
{
    int e = blockIdx.x, tid = threadIdx.x;
    int s = src[e], d = dst[e];
    float alpha = ebuf[e] / ssum[d];
    const float* vr = v + (size_t)s * FDIM;
    float* ar = aggr + (size_t)d * FDIM;
    for (int c = tid; c < FDIM; c += 256) atomicAdd(&ar[c], alpha * vr[c]);
}

// ---------------------------------------------------------------------------
// Persistent 2-layer-of-grid LSTM scan. 32 WGs x 256 threads. Weights (whh,
// 512x2048) live in registers: thread owns column j = gate*512 + w*16 + dl,
// K-segment seg*128..+128. One device-scope grid barrier per timestep; h is
// broadcast through a double-buffered agent-scope atomic buffer (hcur).
// ---------------------------------------------------------------------------
__global__ void __launch_bounds__(256, 1)
lstm_scan(const float* __restrict__ pre, const float* __restrict__ whh,
          float* __restrict__ hseq, float* __restrict__ hcur,
          int* __restrict__ bar, int T)
{
    const int w = blockIdx.x;
    const int tid = threadIdx.x;
    const int dl = tid & 15;
    const int gate = (tid >> 4) & 3;
    const int seg = tid >> 6;
    const int j = gate * 512 + w * 16 + dl;

    float wreg[128];
    {
        const float* wc = whh + (size_t)(seg * 128) * GDIM + j;
#pragma unroll
        for (int kk = 0; kk < 128; kk++) wreg[kk] = wc[(size_t)kk * GDIM];
    }

    __shared__ float h_lds[512];
    __shared__ float red[256];
    __shared__ float gbuf[64];
    for (int i = tid; i < 512; i += 256) h_lds[i] = 0.0f;
    float c = 0.0f;
    float pre_next = (tid < 64) ? pre[j] : 0.0f;
    __syncthreads();

    for (int t = 0; t < T; t++) {
        // matvec partial: sum over this thread's 128-k segment
        const float* hseg = h_lds + seg * 128;
        float a0 = 0, a1 = 0, a2 = 0, a3 = 0;
#pragma unroll
        for (int kk = 0; kk < 128; kk += 4) {
            float4 hv = *(const float4*)(hseg + kk);
            a0 += wreg[kk + 0] * hv.x;
            a1 += wreg[kk + 1] * hv.y;
            a2 += wreg[kk + 2] * hv.z;
            a3 += wreg[kk + 3] * hv.w;
        }
        red[tid] = (a0 + a1) + (a2 + a3);
        __syncthreads();
        if (tid < 64) {
            float tot = red[tid] + red[tid + 64] + red[tid + 128] + red[tid + 192] + pre_next;
            gbuf[tid] = tot;
            if (t + 1 < T) pre_next = pre[(size_t)(t + 1) * GDIM + j];  // prefetch
        }
        __syncthreads();
        if (tid < 16) {
            float ii = gbuf[tid], ff = gbuf[16 + tid], gg = gbuf[32 + tid], oo = gbuf[48 + tid];
            c = sigf(ff) * c + sigf(ii) * tanh_fast(gg);
            float h = sigf(oo) * tanh_fast(c);
            int d = w * 16 + tid;
            hseq[(size_t)t * 512 + d] = h;
            __hip_atomic_store(&hcur[(t & 1) * 512 + d], h,
                               __ATOMIC_RELAXED, __HIP_MEMORY_SCOPE_AGENT);
        }
        __builtin_amdgcn_fence(__ATOMIC_RELEASE, "agent");
        __syncthreads();
        if (tid == 0) {
            __hip_atomic_fetch_add(bar, 1, __ATOMIC_RELEASE, __HIP_MEMORY_SCOPE_AGENT);
            int target = LWG * (t + 1);
            while (__hip_atomic_load(bar, __ATOMIC_RELAXED, __HIP_MEMORY_SCOPE_AGENT) < target)
                __builtin_amdgcn_s_sleep(1);
            __builtin_amdgcn_fence(__ATOMIC_ACQUIRE, "agent");
        }
        __syncthreads();
        const float* hs = hcur + (t & 1) * 512;
        for (int i = tid; i < 512; i += 256)
            h_lds[i] = __hip_atomic_load(hs + i, __ATOMIC_RELAXED, __HIP_MEMORY_SCOPE_AGENT);
        __syncthreads();
    }
}

// ---------------------------------------------------------------------------
__global__ void relu_ip(float* __restrict__ x, int n)
{
    int i = blockIdx.x * blockDim.x + threadIdx.x;
    if (i < n) x[i] = fmaxf(x[i], 0.0f);
}

__global__ void cbf_head(const float* __restrict__ xc, const float* __restrict__ w,
                         const float* __restrict__ b, float* __restrict__ out)
{
    int i = blockIdx.x, tid = threadIdx.x;
    const float* xr = xc + (size_t)i * FDIM;
    float acc = 0.0f;
    for (int d = tid; d < FDIM; d += 64) acc += fmaxf(xr[d], 0.0f) * w[d];
    for (int off = 32; off; off >>= 1) acc += __shfl_down(acc, off);
    if (tid == 0) out[i] = acc + b[0];
}

__global__ void zero_bar(int* __restrict__ bar)
{
    if (threadIdx.x < 16) bar[threadIdx.x] = 0;
}

// ---------------------------------------------------------------------------
extern "C" void kernel_launch(void* const* d_in, const int* in_sizes, int n_in,
                              void* d_out, int out_size, void* d_ws, size_t ws_size,
                              hipStream_t stream)
{
    const float* x      = (const float*)d_in[0];
    const float* states = (const float*)d_in[1];
    const int*   src    = (const int*)d_in[2];
    const int*   dst    = (const int*)d_in[3];
    const float* phi_w0 = (const float*)d_in[4];
    const float* phi_b0 = (const float*)d_in[5];
    const float* phi_w1 = (const float*)d_in[6];
    const float* phi_b1 = (const float*)d_in[7];
    const float* phi_w2 = (const float*)d_in[8];
    const float* phi_b2 = (const float*)d_in[9];
    const float* tq_w = (const float*)d_in[10]; const float* tq_b = (const float*)d_in[11];
    const float* tk_w = (const float*)d_in[12]; const float* tk_b = (const float*)d_in[13];
    const float* tv_w = (const float*)d_in[14]; const float* tv_b = (const float*)d_in[15];
    const float* ts_w = (const float*)d_in[16]; const float* ts_b = (const float*)d_in[17];
    const float* wih0 = (const float*)d_in[18]; const float* whh0 = (const float*)d_in[19];
    const float* b0   = (const float*)d_in[20];
    const float* wih1 = (const float*)d_in[21]; const float* whh1 = (const float*)d_in[22];
    const float* b1   = (const float*)d_in[23];
    const float* cbf_w = (const float*)d_in[24]; const float* cbf_b = (const float*)d_in[25];

    float* ws = (float*)d_ws;
    size_t off = 0;
    auto alloc = [&](size_t n) { float* p = ws + off; off += n; return p; };
    float* xA     = alloc((size_t)NA * FDIM);
    float* xB     = alloc((size_t)NA * FDIM);
    float* phi    = alloc((size_t)NA * FDIM);
    float* qb     = alloc((size_t)NA * FDIM);
    float* kb     = alloc((size_t)NA * FDIM);
    float* vb     = alloc((size_t)NA * FDIM);
    float* aggr   = alloc((size_t)NA * FDIM);
    float* h0     = alloc((size_t)NA * FDIM);
    float* pre    = alloc((size_t)NA * GDIM);
    float* logits = alloc(NA);
    float* mb     = alloc(NA);
    float* ssum   = alloc(NA);
    float* ebuf   = alloc(NA);
    float* hcur   = alloc(1024);
    int*   bar    = (int*)(ws + off);

    float* out_x   = (float*)d_out;
    float* out_cbf = out_x + (size_t)NA * FDIM;

    zero_bar<<<1, 64, 0, stream>>>(bar);

    dim3 g512(FDIM / 64, NA / 64);     // (8, 64)
    dim3 g2048(GDIM / 64, NA / 64);    // (32, 64)

    const float* xin = x;
    int pass = 0;
    for (int l = 0; l < 4; l++) {
        float* xout = (l == 3) ? out_x : ((l & 1) ? xB : xA);

        phi_fused<<<NA, 64, 0, stream>>>(xin, states, src, dst,
            phi_w0 + (size_t)l * 518 * HID, phi_b0 + l * HID,
            phi_w1 + (size_t)l * HID * HID, phi_b1 + l * HID,
            phi_w2 + (size_t)l * HID * FDIM, phi_b2 + l * FDIM, phi);

        gemm64<<<g512, 256, 0, stream>>>(phi, FDIM, phi, FDIM, FDIM,
            tq_w + (size_t)l * FDIM * FDIM, tq_b + l * FDIM, qb, NA, FDIM, FDIM);
        gemm64<<<g512, 256, 0, stream>>>(phi, FDIM, phi, FDIM, FDIM,
            tk_w + (size_t)l * FDIM * FDIM, tk_b + l * FDIM, kb, NA, FDIM, FDIM);
        gemm64<<<g512, 256, 0, stream>>>(phi, FDIM, phi, FDIM, FDIM,
            tv_w + (size_t)l * FDIM * FDIM, tv_b + l * FDIM, vb, NA, FDIM, FDIM);
        gemm64<<<g512, 256, 0, stream>>>(phi, FDIM, phi, FDIM, FDIM,
            ts_w + (size_t)l * FDIM * FDIM, ts_b + l * FDIM, aggr, NA, FDIM, FDIM);

        att_init<<<NA / 256, 256, 0, stream>>>(mb, ssum);
        att_logits<<<NA, 64, 0, stream>>>(qb, kb, src, dst, logits, mb);
        att_expsum<<<NA / 256, 256, 0, stream>>>(logits, mb, dst, ebuf, ssum);
        att_scatter<<<NA, 256, 0, stream>>>(vb, src, dst, ebuf, ssum, aggr);

        // pre0 = [aggr | xin] @ wih0 + b0
        gemm64<<<g2048, 256, 0, stream>>>(aggr, FDIM, xin, FDIM, FDIM,
            wih0 + (size_t)l * 1024 * GDIM, b0 + (size_t)l * GDIM, pre, NA, GDIM, 1024);
        lstm_scan<<<LWG, 256, 0, stream>>>(pre, whh0 + (size_t)l * FDIM * GDIM,
                                           h0, hcur, bar + pass, NA);
        pass++;
        // pre1 = h0 @ wih1 + b1
        gemm64<<<g2048, 256, 0, stream>>>(h0, FDIM, h0, FDIM, FDIM,
            wih1 + (size_t)l * FDIM * GDIM, b1 + (size_t)l * GDIM, pre, NA, GDIM, FDIM);
        lstm_scan<<<LWG, 256, 0, stream>>>(pre, whh1 + (size_t)l * FDIM * GDIM,
                                           xout, hcur, bar + pass, NA);
        pass++;

        if (l == 0 || l == 2)
            relu_ip<<<(NA * FDIM + 255) / 256, 256, 0, stream>>>(xout, NA * FDIM);
        xin = xout;
    }

    cbf_head<<<NA, 64, 0, stream>>>(out_x, cbf_w, cbf_b, out_cbf);
}

// Round 2
// 72487.189 us; speedup vs baseline: 1.8312x; 1.8312x over previous
//
#include <hip/hip_runtime.h>
#include <hip/hip_bf16.h>
#include <math.h>

// Problem constants (from reference)
#define NA   4096      // num agents / edges
#define FDIM 512
#define SDIM 6
#define HID  20
#define GDIM 2048      // 4*FDIM (LSTM gate width)
#define LWG  32        // workgroups in the persistent LSTM kernel

__device__ __forceinline__ float sigf(float x) { return 1.0f / (1.0f + __expf(-x)); }
__device__ __forceinline__ float tanh_fast(float x) {
    // 1 - 2/(exp(2x)+1): exact saturation at +/-1, no inf/inf NaN
    float e = __expf(2.0f * x);
    return 1.0f - 2.0f / (e + 1.0f);
}

__device__ __forceinline__ void atomicMaxF(float* addr, float v) {
    if (v >= 0.0f) atomicMax((int*)addr, __float_as_int(v));
    else           atomicMin((unsigned int*)addr, __float_as_uint(v));
}

// ---------------------------------------------------------------------------
// phi MLP, fused per edge: msg = [xin[src] | states[src]-states[dst]] (518)
// ---------------------------------------------------------------------------
__global__ void phi_fused(const float* __restrict__ xin, const float* __restrict__ states,
                          const int* __restrict__ src, const int* __restrict__ dst,
                          const float* __restrict__ w0, const float* __restrict__ b0,
                          const float* __restrict__ w1, const float* __restrict__ b1,
                          const float* __restrict__ w2, const float* __restrict__ b2,
                          float* __restrict__ phi)
{
    int e = blockIdx.x, tid = threadIdx.x;
    __shared__ float msgv[FDIM + SDIM];
    __shared__ float hb1[HID];
    __shared__ float hb2[HID];
    int s = src[e], d = dst[e];
    for (int i = tid; i < FDIM; i += 64) msgv[i] = xin[(size_t)s * FDIM + i];
    if (tid < SDIM) msgv[FDIM + tid] = states[s * SDIM + tid] - states[d * SDIM + tid];
    __syncthreads();
    if (tid < HID) {
        float acc = b0[tid];
        for (int k = 0; k < FDIM + SDIM; k++) acc += msgv[k] * w0[k * HID + tid];
        hb1[tid] = fmaxf(acc, 0.0f);
    }
    __syncthreads();
    if (tid < HID) {
        float acc = b1[tid];
        for (int k = 0; k < HID; k++) acc += hb1[k] * w1[k * HID + tid];
        hb2[tid] = fmaxf(acc, 0.0f);
    }
    __syncthreads();
    for (int c = tid; c < FDIM; c += 64) {
        float acc = b2[c];
        for (int k = 0; k < HID; k++) acc += hb2[k] * w2[k * FDIM + c];
        phi[(size_t)e * FDIM + c] = acc;
    }
}

// ---------------------------------------------------------------------------
// fp32 tiled GEMM: C[M,N] = A[M,K] @ B[K,N] + bias[N]; A split at col splitA.
// ---------------------------------------------------------------------------
__global__ void __launch_bounds__(256)
gemm64(const float* __restrict__ A1, int lda1,
       const float* __restrict__ A2, int lda2, int splitA,
       const float* __restrict__ B, const float* __restrict__ bias,
       float* __restrict__ C, int M, int N, int K)
{
    __shared__ float a_lds[16][64];
    __shared__ float b_lds[16][64];
    int tid = threadIdx.x;
    int m0 = blockIdx.y * 64, n0 = blockIdx.x * 64;
    int tr = tid >> 2, tc4 = (tid & 3) * 4;
    int bry = tid >> 4, bc4 = (tid & 15) * 4;
    int ty = tid >> 4, tx = tid & 15;
    float acc[4][4] = {};

    for (int kt = 0; kt < K; kt += 16) {
        int ak = kt + tc4;
        const float* arow;
        int acol;
        if (ak < splitA) { arow = A1 + (size_t)(m0 + tr) * lda1; acol = ak; }
        else             { arow = A2 + (size_t)(m0 + tr) * lda2; acol = ak - splitA; }
        float4 av = *(const float4*)(arow + acol);
        a_lds[tc4 + 0][tr] = av.x;
        a_lds[tc4 + 1][tr] = av.y;
        a_lds[tc4 + 2][tr] = av.z;
        a_lds[tc4 + 3][tr] = av.w;
        float4 bv = *(const float4*)(B + (size_t)(kt + bry) * N + n0 + bc4);
        *(float4*)&b_lds[bry][bc4] = bv;
        __syncthreads();
#pragma unroll
        for (int kk = 0; kk < 16; kk++) {
            float4 a = *(const float4*)&a_lds[kk][ty * 4];
            float4 b = *(const float4*)&b_lds[kk][tx * 4];
            acc[0][0] += a.x * b.x; acc[0][1] += a.x * b.y; acc[0][2] += a.x * b.z; acc[0][3] += a.x * b.w;
            acc[1][0] += a.y * b.x; acc[1][1] += a.y * b.y; acc[1][2] += a.y * b.z; acc[1][3] += a.y * b.w;
            acc[2][0] += a.z * b.x; acc[2][1] += a.z * b.y; acc[2][2] += a.z * b.z; acc[2][3] += a.z * b.w;
            acc[3][0] += a.w * b.x; acc[3][1] += a.w * b.y; acc[3][2] += a.w * b.z; acc[3][3] += a.w * b.w;
        }
        __syncthreads();
    }
    float4 bb = *(const float4*)(bias + n0 + tx * 4);
#pragma unroll
    for (int i = 0; i < 4; i++) {
        int row = m0 + ty * 4 + i;
        float4 o;
        o.x = acc[i][0] + bb.x; o.y = acc[i][1] + bb.y; o.z = acc[i][2] + bb.z; o.w = acc[i][3] + bb.w;
        *(float4*)&C[(size_t)row * N + n0 + tx * 4] = o;
    }
}

// ---------------------------------------------------------------------------
// attention (generic segment softmax; with dst=arange it is singleton/exact)
// ---------------------------------------------------------------------------
__global__ void att_init(float* __restrict__ m, float* __restrict__ ssum)
{
    int i = blockIdx.x * blockDim.x + threadIdx.x;
    if (i < NA) { m[i] = -INFINITY; ssum[i] = 0.0f; }
}

__global__ void att_logits(const float* __restrict__ q, const float* __restrict__ k,
                           const int* __restrict__ src, const int* __restrict__ dst,
                           float* __restrict__ logits, float* __restrict__ m)
{
    int e = blockIdx.x, tid = threadIdx.x;
    int s = src[e], d = dst[e];
    const float4* qr = (const float4*)(q + (size_t)d * FDIM);
    const float4* kr = (const float4*)(k + (size_t)s * FDIM);
    float acc = 0.0f;
    for (int i = tid; i < FDIM / 4; i += 64) {
        float4 a = qr[i], b = kr[i];
        acc += a.x * b.x + a.y * b.y + a.z * b.z + a.w * b.w;
    }
    for (int off = 32; off; off >>= 1) acc += __shfl_down(acc, off);
    if (tid == 0) {
        float v = acc * 0.04419417382415922f;   // 1/sqrt(512)
        logits[e] = v;
        atomicMaxF(&m[d], v);
    }
}

__global__ void att_expsum(const float* __restrict__ logits, const float* __restrict__ m,
                           const int* __restrict__ dst,
                           float* __restrict__ ebuf, float* __restrict__ ssum)
{
    int e = blockIdx.x * blockDim.x + threadIdx.x;
    if (e < NA) {
        float v = __expf(logits[e] - m[dst[e]]);
        ebuf[e] = v;
        atomicAdd(&ssum[dst[e]], v);
    }
}

__global__ void att_scatter(const float* __restrict__ v, const int* __restrict__ src,
                            const int* __restrict__ dst, const float* __restrict__ ebuf,
                            const float* __restrict__ ssum, float* __restrict__ aggr)
{
    int e = blockIdx.x, tid = threadIdx.x;
    int s = src[e], d = dst[e];
    float alpha = ebuf[e] / ssum[d];
    const float* vr = v + (size_t)s * FDIM;
    float* ar = aggr + (size_t)d * FDIM;
    for (int c = tid; c < FDIM; c += 256) atomicAdd(&ar[c], alpha * vr[c]);
}

// ---------------------------------------------------------------------------
// Persistent LSTM scan, fence-free tagged broadcast.
// Each of 512 h-lanes is published as one aligned 64-bit word:
//   (tag << 32) | float_bits(h),  tag = tagbase + t + 1  (unique per launch).
// Single-word atomicity => no fences, no counter barrier. Double-buffered by
// t&1; exact-tag match + transitive publish dependency bounds producer lead
// to <2 steps, so no overwrite hazard.
// ---------------------------------------------------------------------------
__global__ void __launch_bounds__(256, 1)
lstm_scan(const float* __restrict__ pre, const float* __restrict__ whh,
          float* __restrict__ hseq, unsigned long long* __restrict__ hbuf,
          unsigned int tagbase, int T)
{
    const int w = blockIdx.x;
    const int tid = threadIdx.x;
    const int dl = tid & 15;
    const int gate = (tid >> 4) & 3;
    const int seg = tid >> 6;
    const int j = gate * 512 + w * 16 + dl;

    float wreg[128];
    {
        const float* wc = whh + (size_t)(seg * 128) * GDIM + j;
#pragma unroll
        for (int kk = 0; kk < 128; kk++) wreg[kk] = wc[(size_t)kk * GDIM];
    }

    __shared__ float h_lds[512];
    __shared__ float red[256];
    __shared__ float gbuf[64];
    for (int i = tid; i < 512; i += 256) h_lds[i] = 0.0f;
    float c = 0.0f;
    float pre_next = (tid < 64) ? pre[j] : 0.0f;
    __syncthreads();

    for (int t = 0; t < T; t++) {
        // matvec partial over this thread's 128-k segment
        const float* hseg = h_lds + seg * 128;
        float a0 = 0, a1 = 0, a2 = 0, a3 = 0;
#pragma unroll
        for (int kk = 0; kk < 128; kk += 4) {
            float4 hv = *(const float4*)(hseg + kk);
            a0 += wreg[kk + 0] * hv.x;
            a1 += wreg[kk + 1] * hv.y;
            a2 += wreg[kk + 2] * hv.z;
            a3 += wreg[kk + 3] * hv.w;
        }
        red[tid] = (a0 + a1) + (a2 + a3);
        __syncthreads();          // also: all matvec reads of h_lds done
        if (tid < 64) {
            float tot = red[tid] + red[tid + 64] + red[tid + 128] + red[tid + 192] + pre_next;
            gbuf[tid] = tot;
            if (t + 1 < T) pre_next = pre[(size_t)(t + 1) * GDIM + j];  // prefetch
        }
        __syncthreads();
        if (tid < 16) {
            float ii = gbuf[tid], ff = gbuf[16 + tid], gg = gbuf[32 + tid], oo = gbuf[48 + tid];
            c = sigf(ff) * c + sigf(ii) * tanh_fast(gg);
            float h = sigf(oo) * tanh_fast(c);
            int d = w * 16 + tid;
            hseq[(size_t)t * 512 + d] = h;
            unsigned long long word =
                ((unsigned long long)(tagbase + (unsigned)t + 1u) << 32) |
                (unsigned long long)__float_as_uint(h);
            __hip_atomic_store(&hbuf[(t & 1) * 512 + d], word,
                               __ATOMIC_RELAXED, __HIP_MEMORY_SCOPE_AGENT);
        }
        if (t + 1 < T) {
            unsigned long long want = (unsigned long long)(tagbase + (unsigned)t + 1u);
            unsigned long long* p0 = &hbuf[(t & 1) * 512 + tid];
            unsigned long long* p1 = p0 + 256;
            unsigned long long a = __hip_atomic_load(p0, __ATOMIC_RELAXED, __HIP_MEMORY_SCOPE_AGENT);
            unsigned long long b = __hip_atomic_load(p1, __ATOMIC_RELAXED, __HIP_MEMORY_SCOPE_AGENT);
            while ((a >> 32) != want)
                a = __hip_atomic_load(p0, __ATOMIC_RELAXED, __HIP_MEMORY_SCOPE_AGENT);
            while ((b >> 32) != want)
                b = __hip_atomic_load(p1, __ATOMIC_RELAXED, __HIP_MEMORY_SCOPE_AGENT);
            h_lds[tid]       = __uint_as_float((unsigned int)a);
            h_lds[tid + 256] = __uint_as_float((unsigned int)b);
            __syncthreads();
        }
    }
}

// ---------------------------------------------------------------------------
__global__ void relu_ip(float* __restrict__ x, int n)
{
    int i = blockIdx.x * blockDim.x + threadIdx.x;
    if (i < n) x[i] = fmaxf(x[i], 0.0f);
}

__global__ void cbf_head(const float* __restrict__ xc, const float* __restrict__ w,
                         const float* __restrict__ b, float* __restrict__ out)
{
    int i = blockIdx.x, tid = threadIdx.x;
    const float* xr = xc + (size_t)i * FDIM;
    float acc = 0.0f;
    for (int d = tid; d < FDIM; d += 64) acc += fmaxf(xr[d], 0.0f) * w[d];
    for (int off = 32; off; off >>= 1) acc += __shfl_down(acc, off);
    if (tid == 0) out[i] = acc + b[0];
}

__global__ void zero_hbuf(unsigned long long* __restrict__ hbuf)
{
    int i = blockIdx.x * blockDim.x + threadIdx.x;
    if (i < 1024) hbuf[i] = 0ull;
}

// ---------------------------------------------------------------------------
extern "C" void kernel_launch(void* const* d_in, const int* in_sizes, int n_in,
                              void* d_out, int out_size, void* d_ws, size_t ws_size,
                              hipStream_t stream)
{
    const float* x      = (const float*)d_in[0];
    const float* states = (const float*)d_in[1];
    const int*   src    = (const int*)d_in[2];
    const int*   dst    = (const int*)d_in[3];
    const float* phi_w0 = (const float*)d_in[4];
    const float* phi_b0 = (const float*)d_in[5];
    const float* phi_w1 = (const float*)d_in[6];
    const float* phi_b1 = (const float*)d_in[7];
    const float* phi_w2 = (const float*)d_in[8];
    const float* phi_b2 = (const float*)d_in[9];
    const float* tq_w = (const float*)d_in[10]; const float* tq_b = (const float*)d_in[11];
    const float* tk_w = (const float*)d_in[12]; const float* tk_b = (const float*)d_in[13];
    const float* tv_w = (const float*)d_in[14]; const float* tv_b = (const float*)d_in[15];
    const float* ts_w = (const float*)d_in[16]; const float* ts_b = (const float*)d_in[17];
    const float* wih0 = (const float*)d_in[18]; const float* whh0 = (const float*)d_in[19];
    const float* b0   = (const float*)d_in[20];
    const float* wih1 = (const float*)d_in[21]; const float* whh1 = (const float*)d_in[22];
    const float* b1   = (const float*)d_in[23];
    const float* cbf_w = (const float*)d_in[24]; const float* cbf_b = (const float*)d_in[25];

    float* ws = (float*)d_ws;
    size_t off = 0;
    auto alloc = [&](size_t n) { float* p = ws + off; off += n; return p; };
    float* xA     = alloc((size_t)NA * FDIM);
    float* xB     = alloc((size_t)NA * FDIM);
    float* phi    = alloc((size_t)NA * FDIM);
    float* qb     = alloc((size_t)NA * FDIM);
    float* kb     = alloc((size_t)NA * FDIM);
    float* vb     = alloc((size_t)NA * FDIM);
    float* aggr   = alloc((size_t)NA * FDIM);
    float* h0     = alloc((size_t)NA * FDIM);
    float* pre    = alloc((size_t)NA * GDIM);
    float* logits = alloc(NA);
    float* mb     = alloc(NA);
    float* ssum   = alloc(NA);
    float* ebuf   = alloc(NA);
    unsigned long long* hbuf = (unsigned long long*)alloc(2048);  // 1024 u64, 8B-aligned

    float* out_x   = (float*)d_out;
    float* out_cbf = out_x + (size_t)NA * FDIM;

    zero_hbuf<<<4, 256, 0, stream>>>(hbuf);

    dim3 g512(FDIM / 64, NA / 64);     // (8, 64)
    dim3 g2048(GDIM / 64, NA / 64);    // (32, 64)

    const float* xin = x;
    unsigned int pass = 0;
    for (int l = 0; l < 4; l++) {
        float* xout = (l == 3) ? out_x : ((l & 1) ? xB : xA);

        phi_fused<<<NA, 64, 0, stream>>>(xin, states, src, dst,
            phi_w0 + (size_t)l * 518 * HID, phi_b0 + l * HID,
            phi_w1 + (size_t)l * HID * HID, phi_b1 + l * HID,
            phi_w2 + (size_t)l * HID * FDIM, phi_b2 + l * FDIM, phi);

        gemm64<<<g512, 256, 0, stream>>>(phi, FDIM, phi, FDIM, FDIM,
            tq_w + (size_t)l * FDIM * FDIM, tq_b + l * FDIM, qb, NA, FDIM, FDIM);
        gemm64<<<g512, 256, 0, stream>>>(phi, FDIM, phi, FDIM, FDIM,
            tk_w + (size_t)l * FDIM * FDIM, tk_b + l * FDIM, kb, NA, FDIM, FDIM);
        gemm64<<<g512, 256, 0, stream>>>(phi, FDIM, phi, FDIM, FDIM,
            tv_w + (size_t)l * FDIM * FDIM, tv_b + l * FDIM, vb, NA, FDIM, FDIM);
        gemm64<<<g512, 256, 0, stream>>>(phi, FDIM, phi, FDIM, FDIM,
            ts_w + (size_t)l * FDIM * FDIM, ts_b + l * FDIM, aggr, NA, FDIM, FDIM);

        att_init<<<NA / 256, 256, 0, stream>>>(mb, ssum);
        att_logits<<<NA, 64, 0, stream>>>(qb, kb, src, dst, logits, mb);
        att_expsum<<<NA / 256, 256, 0, stream>>>(logits, mb, dst, ebuf, ssum);
        att_scatter<<<NA, 256, 0, stream>>>(vb, src, dst, ebuf, ssum, aggr);

        // pre0 = [aggr | xin] @ wih0 + b0
        gemm64<<<g2048, 256, 0, stream>>>(aggr, FDIM, xin, FDIM, FDIM,
            wih0 + (size_t)l * 1024 * GDIM, b0 + (size_t)l * GDIM, pre, NA, GDIM, 1024);
        lstm_scan<<<LWG, 256, 0, stream>>>(pre, whh0 + (size_t)l * FDIM * GDIM,
                                           h0, hbuf, pass * (unsigned)NA, NA);
        pass++;
        // pre1 = h0 @ wih1 + b1
        gemm64<<<g2048, 256, 0, stream>>>(h0, FDIM, h0, FDIM, FDIM,
            wih1 + (size_t)l * FDIM * GDIM, b1 + (size_t)l * GDIM, pre, NA, GDIM, FDIM);
        lstm_scan<<<LWG, 256, 0, stream>>>(pre, whh1 + (size_t)l * FDIM * GDIM,
                                           xout, hbuf, pass * (unsigned)NA, NA);
        pass++;

        if (l == 0 || l == 2)
            relu_ip<<<(NA * FDIM + 255) / 256, 256, 0, stream>>>(xout, NA * FDIM);
        xin = xout;
    }

    cbf_head<<<NA, 64, 0, stream>>>(out_x, cbf_w, cbf_b, out_cbf);
}

// Round 3
// 38755.109 us; speedup vs baseline: 3.4250x; 1.8704x over previous
//
#include <hip/hip_runtime.h>
#include <hip/hip_bf16.h>
#include <math.h>

// Problem constants (from reference)
#define NA   4096      // num agents / edges
#define FDIM 512
#define SDIM 6
#define HID  20
#define GDIM 2048      // 4*FDIM (LSTM gate width)
#define LWG  32        // WGs per LSTM role in the persistent pair kernel

__device__ __forceinline__ float sigf(float x) { return 1.0f / (1.0f + __expf(-x)); }
__device__ __forceinline__ float tanh_fast(float x) {
    // 1 - 2/(exp(2x)+1): exact saturation at +/-1, no inf/inf NaN
    float e = __expf(2.0f * x);
    return 1.0f - 2.0f / (e + 1.0f);
}

__device__ __forceinline__ void atomicMaxF(float* addr, float v) {
    if (v >= 0.0f) atomicMax((int*)addr, __float_as_int(v));
    else           atomicMin((unsigned int*)addr, __float_as_uint(v));
}

// ---------------------------------------------------------------------------
// phi MLP, fused per edge: msg = [xin[src] | states[src]-states[dst]] (518)
// ---------------------------------------------------------------------------
__global__ void phi_fused(const float* __restrict__ xin, const float* __restrict__ states,
                          const int* __restrict__ src, const int* __restrict__ dst,
                          const float* __restrict__ w0, const float* __restrict__ b0,
                          const float* __restrict__ w1, const float* __restrict__ b1,
                          const float* __restrict__ w2, const float* __restrict__ b2,
                          float* __restrict__ phi)
{
    int e = blockIdx.x, tid = threadIdx.x;
    __shared__ float msgv[FDIM + SDIM];
    __shared__ float hb1[HID];
    __shared__ float hb2[HID];
    int s = src[e], d = dst[e];
    for (int i = tid; i < FDIM; i += 64) msgv[i] = xin[(size_t)s * FDIM + i];
    if (tid < SDIM) msgv[FDIM + tid] = states[s * SDIM + tid] - states[d * SDIM + tid];
    __syncthreads();
    if (tid < HID) {
        float acc = b0[tid];
        for (int k = 0; k < FDIM + SDIM; k++) acc += msgv[k] * w0[k * HID + tid];
        hb1[tid] = fmaxf(acc, 0.0f);
    }
    __syncthreads();
    if (tid < HID) {
        float acc = b1[tid];
        for (int k = 0; k < HID; k++) acc += hb1[k] * w1[k * HID + tid];
        hb2[tid] = fmaxf(acc, 0.0f);
    }
    __syncthreads();
    for (int c = tid; c < FDIM; c += 64) {
        float acc = b2[c];
        for (int k = 0; k < HID; k++) acc += hb2[k] * w2[k * FDIM + c];
        phi[(size_t)e * FDIM + c] = acc;
    }
}

// ---------------------------------------------------------------------------
// fp32 tiled GEMM: C[M,N] = A[M,K] @ B[K,N] + bias[N]; A split at col splitA.
// ---------------------------------------------------------------------------
__global__ void __launch_bounds__(256)
gemm64(const float* __restrict__ A1, int lda1,
       const float* __restrict__ A2, int lda2, int splitA,
       const float* __restrict__ B, const float* __restrict__ bias,
       float* __restrict__ C, int M, int N, int K)
{
    __shared__ float a_lds[16][64];
    __shared__ float b_lds[16][64];
    int tid = threadIdx.x;
    int m0 = blockIdx.y * 64, n0 = blockIdx.x * 64;
    int tr = tid >> 2, tc4 = (tid & 3) * 4;
    int bry = tid >> 4, bc4 = (tid & 15) * 4;
    int ty = tid >> 4, tx = tid & 15;
    float acc[4][4] = {};

    for (int kt = 0; kt < K; kt += 16) {
        int ak = kt + tc4;
        const float* arow;
        int acol;
        if (ak < splitA) { arow = A1 + (size_t)(m0 + tr) * lda1; acol = ak; }
        else             { arow = A2 + (size_t)(m0 + tr) * lda2; acol = ak - splitA; }
        float4 av = *(const float4*)(arow + acol);
        a_lds[tc4 + 0][tr] = av.x;
        a_lds[tc4 + 1][tr] = av.y;
        a_lds[tc4 + 2][tr] = av.z;
        a_lds[tc4 + 3][tr] = av.w;
        float4 bv = *(const float4*)(B + (size_t)(kt + bry) * N + n0 + bc4);
        *(float4*)&b_lds[bry][bc4] = bv;
        __syncthreads();
#pragma unroll
        for (int kk = 0; kk < 16; kk++) {
            float4 a = *(const float4*)&a_lds[kk][ty * 4];
            float4 b = *(const float4*)&b_lds[kk][tx * 4];
            acc[0][0] += a.x * b.x; acc[0][1] += a.x * b.y; acc[0][2] += a.x * b.z; acc[0][3] += a.x * b.w;
            acc[1][0] += a.y * b.x; acc[1][1] += a.y * b.y; acc[1][2] += a.y * b.z; acc[1][3] += a.y * b.w;
            acc[2][0] += a.z * b.x; acc[2][1] += a.z * b.y; acc[2][2] += a.z * b.z; acc[2][3] += a.z * b.w;
            acc[3][0] += a.w * b.x; acc[3][1] += a.w * b.y; acc[3][2] += a.w * b.z; acc[3][3] += a.w * b.w;
        }
        __syncthreads();
    }
    float4 bb = *(const float4*)(bias + n0 + tx * 4);
#pragma unroll
    for (int i = 0; i < 4; i++) {
        int row = m0 + ty * 4 + i;
        float4 o;
        o.x = acc[i][0] + bb.x; o.y = acc[i][1] + bb.y; o.z = acc[i][2] + bb.z; o.w = acc[i][3] + bb.w;
        *(float4*)&C[(size_t)row * N + n0 + tx * 4] = o;
    }
}

// ---------------------------------------------------------------------------
// attention (generic segment softmax; with dst=arange it is singleton/exact)
// ---------------------------------------------------------------------------
__global__ void att_init(float* __restrict__ m, float* __restrict__ ssum)
{
    int i = blockIdx.x * blockDim.x + threadIdx.x;
    if (i < NA) { m[i] = -INFINITY; ssum[i] = 0.0f; }
}

__global__ void att_logits(const float* __restrict__ q, const float* __restrict__ k,
                           const int* __restrict__ src, const int* __restrict__ dst,
                           float* __restrict__ logits, float* __restrict__ m)
{
    int e = blockIdx.x, tid = threadIdx.x;
    int s = src[e], d = dst[e];
    const float4* qr = (const float4*)(q + (size_t)d * FDIM);
    const float4* kr = (const float4*)(k + (size_t)s * FDIM);
    float acc = 0.0f;
    for (int i = tid; i < FDIM / 4; i += 64) {
        float4 a = qr[i], b = kr[i];
        acc += a.x * b.x + a.y * b.y + a.z * b.z + a.w * b.w;
    }
    for (int off = 32; off; off >>= 1) acc += __shfl_down(acc, off);
    if (tid == 0) {
        float v = acc * 0.04419417382415922f;   // 1/sqrt(512)
        logits[e] = v;
        atomicMaxF(&m[d], v);
    }
}

__global__ void att_expsum(const float* __restrict__ logits, const float* __restrict__ m,
                           const int* __restrict__ dst,
                           float* __restrict__ ebuf, float* __restrict__ ssum)
{
    int e = blockIdx.x * blockDim.x + threadIdx.x;
    if (e < NA) {
        float v = __expf(logits[e] - m[dst[e]]);
        ebuf[e] = v;
        atomicAdd(&ssum[dst[e]], v);
    }
}

__global__ void att_scatter(const float* __restrict__ v, const int* __restrict__ src,
                            const int* __restrict__ dst, const float* __restrict__ ebuf,
                            const float* __restrict__ ssum, float* __restrict__ aggr)
{
    int e = blockIdx.x, tid = threadIdx.x;
    int s = src[e], d = dst[e];
    float alpha = ebuf[e] / ssum[d];
    const float* vr = v + (size_t)s * FDIM;
    float* ar = aggr + (size_t)d * FDIM;
    for (int c = tid; c < FDIM; c += 256) atomicAdd(&ar[c], alpha * vr[c]);
}

// ---------------------------------------------------------------------------
// Pipelined 2-layer LSTM scan. 64 WGs x 512 threads.
//  Role A (WG 0..31): LSTM0. whh0 columns in registers (64 f32/thread).
//    Publishes h0(t) tagged into write-once hfull[t*512+d]; its own
//    recurrence also reads hfull. Never waits on role B (no overwrite:
//    fresh region per step).
//  Role B (WG 32..63): LSTM1 WITH fused input transform:
//    gate_j = b1[j] + [h0(t); h1(t-1)] . [wih1;whh1][:,j]
//    (128 f32 weights/thread). Polls hfull for h0(t); h1 peer exchange via
//    2-slot tagged hbuf1 (overwrite-safe by transitive publish dependency).
// Tags: pass*NA + t + 1, unique per call; hfull/hbuf1 zeroed at launch start
// so graph replays cannot alias tags.
// ---------------------------------------------------------------------------
__global__ void __launch_bounds__(512, 2)
lstm_pair(const float* __restrict__ pre0, const float* __restrict__ whh0,
          const float* __restrict__ wih1, const float* __restrict__ whh1,
          const float* __restrict__ b1,
          float* __restrict__ xout,
          unsigned long long* __restrict__ hfull,
          unsigned long long* __restrict__ hbuf1,
          unsigned int tag0, unsigned int tag1, int T)
{
    const int wg = blockIdx.x;
    const bool roleB = wg >= LWG;
    const int w = wg & (LWG - 1);
    const int tid = threadIdx.x;
    const int dl = tid & 15;
    const int gate = (tid >> 4) & 3;
    const int seg = tid >> 6;                // 0..7
    const int j = gate * 512 + w * 16 + dl;  // gate column

    float wreg[128];
    if (!roleB) {
        const float* wc = whh0 + (size_t)(seg * 64) * GDIM + j;
#pragma unroll
        for (int kk = 0; kk < 64; kk++) wreg[kk] = wc[(size_t)kk * GDIM];
    } else {
        const float* wc = (seg < 4)
            ? (wih1 + (size_t)(seg * 128) * GDIM + j)
            : (whh1 + (size_t)((seg - 4) * 128) * GDIM + j);
#pragma unroll
        for (int kk = 0; kk < 128; kk++) wreg[kk] = wc[(size_t)kk * GDIM];
    }

    __shared__ float h_lds[1024];   // A: [0:512]=h0(t-1). B: [0:512]=h0(t), [512:1024]=h1(t-1)
    __shared__ float red[512];
    __shared__ float gbuf[64];
    float c = 0.0f;
    float extra = 0.0f;             // A: pre0 row prefetch; B: bias
    if (tid < 64) extra = roleB ? b1[j] : pre0[j];
    if (!roleB) h_lds[tid] = 0.0f;
    else        h_lds[512 + tid] = 0.0f;
    __syncthreads();

    if (!roleB) {
        for (int t = 0; t < T; t++) {
            const float* hseg = h_lds + seg * 64;
            float a0 = 0, a1 = 0, a2 = 0, a3 = 0;
#pragma unroll
            for (int kk = 0; kk < 64; kk += 4) {
                float4 hv = *(const float4*)(hseg + kk);
                a0 += wreg[kk + 0] * hv.x;
                a1 += wreg[kk + 1] * hv.y;
                a2 += wreg[kk + 2] * hv.z;
                a3 += wreg[kk + 3] * hv.w;
            }
            red[tid] = (a0 + a1) + (a2 + a3);
            __syncthreads();
            if (tid < 64) {
                float tot = extra;
#pragma unroll
                for (int s = 0; s < 8; s++) tot += red[tid + 64 * s];
                gbuf[tid] = tot;
                if (t + 1 < T) extra = pre0[(size_t)(t + 1) * GDIM + j];  // prefetch
            }
            __syncthreads();
            if (tid < 16) {
                float ii = gbuf[tid], ff = gbuf[16 + tid], gg = gbuf[32 + tid], oo = gbuf[48 + tid];
                c = sigf(ff) * c + sigf(ii) * tanh_fast(gg);
                float h = sigf(oo) * tanh_fast(c);
                unsigned long long word =
                    ((unsigned long long)(tag0 + (unsigned)t + 1u) << 32) |
                    (unsigned long long)__float_as_uint(h);
                __hip_atomic_store(&hfull[(size_t)t * 512 + w * 16 + tid], word,
                                   __ATOMIC_RELAXED, __HIP_MEMORY_SCOPE_AGENT);
            }
            if (t + 1 < T) {
                unsigned long long want = tag0 + (unsigned)t + 1u;
                const unsigned long long* p = &hfull[(size_t)t * 512 + tid];
                unsigned long long v = __hip_atomic_load(p, __ATOMIC_RELAXED, __HIP_MEMORY_SCOPE_AGENT);
                while ((v >> 32) != want)
                    v = __hip_atomic_load(p, __ATOMIC_RELAXED, __HIP_MEMORY_SCOPE_AGENT);
                h_lds[tid] = __uint_as_float((unsigned)v);
                __syncthreads();
            }
        }
    } else {
        for (int t = 0; t < T; t++) {
            {   // poll h0(t)
                unsigned long long want = tag0 + (unsigned)t + 1u;
                const unsigned long long* p = &hfull[(size_t)t * 512 + tid];
                unsigned long long v = __hip_atomic_load(p, __ATOMIC_RELAXED, __HIP_MEMORY_SCOPE_AGENT);
                while ((v >> 32) != want)
                    v = __hip_atomic_load(p, __ATOMIC_RELAXED, __HIP_MEMORY_SCOPE_AGENT);
                h_lds[tid] = __uint_as_float((unsigned)v);
            }
            __syncthreads();
            const float* hseg = h_lds + seg * 128;   // covers [h0 ; h1] concat
            float a0 = 0, a1 = 0, a2 = 0, a3 = 0;
#pragma unroll
            for (int kk = 0; kk < 128; kk += 4) {
                float4 hv = *(const float4*)(hseg + kk);
                a0 += wreg[kk + 0] * hv.x;
                a1 += wreg[kk + 1] * hv.y;
                a2 += wreg[kk + 2] * hv.z;
                a3 += wreg[kk + 3] * hv.w;
            }
            red[tid] = (a0 + a1) + (a2 + a3);
            __syncthreads();
            if (tid < 64) {
                float tot = extra;   // bias b1[j]
#pragma unroll
                for (int s = 0; s < 8; s++) tot += red[tid + 64 * s];
                gbuf[tid] = tot;
            }
            __syncthreads();
            if (tid < 16) {
                float ii = gbuf[tid], ff = gbuf[16 + tid], gg = gbuf[32 + tid], oo = gbuf[48 + tid];
                c = sigf(ff) * c + sigf(ii) * tanh_fast(gg);
                float h = sigf(oo) * tanh_fast(c);
                xout[(size_t)t * 512 + w * 16 + tid] = h;
                unsigned long long word =
                    ((unsigned long long)(tag1 + (unsigned)t + 1u) << 32) |
                    (unsigned long long)__float_as_uint(h);
                __hip_atomic_store(&hbuf1[(t & 1) * 512 + w * 16 + tid], word,
                                   __ATOMIC_RELAXED, __HIP_MEMORY_SCOPE_AGENT);
            }
            if (t + 1 < T) {
                unsigned long long want = tag1 + (unsigned)t + 1u;
                const unsigned long long* p = &hbuf1[(t & 1) * 512 + tid];
                unsigned long long v = __hip_atomic_load(p, __ATOMIC_RELAXED, __HIP_MEMORY_SCOPE_AGENT);
                while ((v >> 32) != want)
                    v = __hip_atomic_load(p, __ATOMIC_RELAXED, __HIP_MEMORY_SCOPE_AGENT);
                h_lds[512 + tid] = __uint_as_float((unsigned)v);
                __syncthreads();
            }
        }
    }
}

// ---------------------------------------------------------------------------
__global__ void relu_ip(float* __restrict__ x, int n)
{
    int i = blockIdx.x * blockDim.x + threadIdx.x;
    if (i < n) x[i] = fmaxf(x[i], 0.0f);
}

__global__ void cbf_head(const float* __restrict__ xc, const float* __restrict__ w,
                         const float* __restrict__ b, float* __restrict__ out)
{
    int i = blockIdx.x, tid = threadIdx.x;
    const float* xr = xc + (size_t)i * FDIM;
    float acc = 0.0f;
    for (int d = tid; d < FDIM; d += 64) acc += fmaxf(xr[d], 0.0f) * w[d];
    for (int off = 32; off; off >>= 1) acc += __shfl_down(acc, off);
    if (tid == 0) out[i] = acc + b[0];
}

__global__ void zero_u64(unsigned long long* __restrict__ p, int n)
{
    int i = blockIdx.x * blockDim.x + threadIdx.x;
    int stride = gridDim.x * blockDim.x;
    for (; i < n; i += stride) p[i] = 0ull;
}

// ---------------------------------------------------------------------------
extern "C" void kernel_launch(void* const* d_in, const int* in_sizes, int n_in,
                              void* d_out, int out_size, void* d_ws, size_t ws_size,
                              hipStream_t stream)
{
    const float* x      = (const float*)d_in[0];
    const float* states = (const float*)d_in[1];
    const int*   src    = (const int*)d_in[2];
    const int*   dst    = (const int*)d_in[3];
    const float* phi_w0 = (const float*)d_in[4];
    const float* phi_b0 = (const float*)d_in[5];
    const float* phi_w1 = (const float*)d_in[6];
    const float* phi_b1 = (const float*)d_in[7];
    const float* phi_w2 = (const float*)d_in[8];
    const float* phi_b2 = (const float*)d_in[9];
    const float* tq_w = (const float*)d_in[10]; const float* tq_b = (const float*)d_in[11];
    const float* tk_w = (const float*)d_in[12]; const float* tk_b = (const float*)d_in[13];
    const float* tv_w = (const float*)d_in[14]; const float* tv_b = (const float*)d_in[15];
    const float* ts_w = (const float*)d_in[16]; const float* ts_b = (const float*)d_in[17];
    const float* wih0 = (const float*)d_in[18]; const float* whh0 = (const float*)d_in[19];
    const float* b0   = (const float*)d_in[20];
    const float* wih1 = (const float*)d_in[21]; const float* whh1 = (const float*)d_in[22];
    const float* b1   = (const float*)d_in[23];
    const float* cbf_w = (const float*)d_in[24]; const float* cbf_b = (const float*)d_in[25];

    float* ws = (float*)d_ws;
    size_t off = 0;
    auto alloc = [&](size_t n) { float* p = ws + off; off += n; return p; };
    float* xA     = alloc((size_t)NA * FDIM);
    float* xB     = alloc((size_t)NA * FDIM);
    float* phi    = alloc((size_t)NA * FDIM);
    float* qb     = alloc((size_t)NA * FDIM);
    float* kb     = alloc((size_t)NA * FDIM);
    float* vb     = alloc((size_t)NA * FDIM);
    float* aggr   = alloc((size_t)NA * FDIM);
    float* pre    = alloc((size_t)NA * GDIM);
    float* logits = alloc(NA);
    float* mb     = alloc(NA);
    float* ssum   = alloc(NA);
    float* ebuf   = alloc(NA);
    const int HFULL_WORDS = NA * 512;       // 2,097,152 u64
    unsigned long long* hfull = (unsigned long long*)alloc((size_t)2 * (HFULL_WORDS + 1024));
    unsigned long long* hbuf1 = hfull + HFULL_WORDS;

    float* out_x   = (float*)d_out;
    float* out_cbf = out_x + (size_t)NA * FDIM;

    zero_u64<<<2048, 256, 0, stream>>>(hfull, HFULL_WORDS + 1024);

    dim3 g512(FDIM / 64, NA / 64);     // (8, 64)
    dim3 g2048(GDIM / 64, NA / 64);    // (32, 64)

    const float* xin = x;
    for (int l = 0; l < 4; l++) {
        float* xout = (l == 3) ? out_x : ((l & 1) ? xB : xA);

        phi_fused<<<NA, 64, 0, stream>>>(xin, states, src, dst,
            phi_w0 + (size_t)l * 518 * HID, phi_b0 + l * HID,
            phi_w1 + (size_t)l * HID * HID, phi_b1 + l * HID,
            phi_w2 + (size_t)l * HID * FDIM, phi_b2 + l * FDIM, phi);

        gemm64<<<g512, 256, 0, stream>>>(phi, FDIM, phi, FDIM, FDIM,
            tq_w + (size_t)l * FDIM * FDIM, tq_b + l * FDIM, qb, NA, FDIM, FDIM);
        gemm64<<<g512, 256, 0, stream>>>(phi, FDIM, phi, FDIM, FDIM,
            tk_w + (size_t)l * FDIM * FDIM, tk_b + l * FDIM, kb, NA, FDIM, FDIM);
        gemm64<<<g512, 256, 0, stream>>>(phi, FDIM, phi, FDIM, FDIM,
            tv_w + (size_t)l * FDIM * FDIM, tv_b + l * FDIM, vb, NA, FDIM, FDIM);
        gemm64<<<g512, 256, 0, stream>>>(phi, FDIM, phi, FDIM, FDIM,
            ts_w + (size_t)l * FDIM * FDIM, ts_b + l * FDIM, aggr, NA, FDIM, FDIM);

        att_init<<<NA / 256, 256, 0, stream>>>(mb, ssum);
        att_logits<<<NA, 64, 0, stream>>>(qb, kb, src, dst, logits, mb);
        att_expsum<<<NA / 256, 256, 0, stream>>>(logits, mb, dst, ebuf, ssum);
        att_scatter<<<NA, 256, 0, stream>>>(vb, src, dst, ebuf, ssum, aggr);

        // pre0 = [aggr | xin] @ wih0 + b0
        gemm64<<<g2048, 256, 0, stream>>>(aggr, FDIM, xin, FDIM, FDIM,
            wih0 + (size_t)l * 1024 * GDIM, b0 + (size_t)l * GDIM, pre, NA, GDIM, 1024);

        // fused, pipelined LSTM0+LSTM1 (pre1 GEMM folded into role B)
        lstm_pair<<<2 * LWG, 512, 0, stream>>>(pre,
            whh0 + (size_t)l * FDIM * GDIM,
            wih1 + (size_t)l * FDIM * GDIM,
            whh1 + (size_t)l * FDIM * GDIM,
            b1 + (size_t)l * GDIM,
            xout, hfull, hbuf1,
            (unsigned)(2 * l) * NA, (unsigned)(2 * l + 1) * NA, NA);

        if (l == 0 || l == 2)
            relu_ip<<<(NA * FDIM + 255) / 256, 256, 0, stream>>>(xout, NA * FDIM);
        xin = xout;
    }

    cbf_head<<<NA, 64, 0, stream>>>(out_x, cbf_w, cbf_b, out_cbf);
}

// Round 4
// 38413.663 us; speedup vs baseline: 3.4554x; 1.0089x over previous
//
#include <hip/hip_runtime.h>
#include <hip/hip_bf16.h>
#include <math.h>

// Problem constants (from reference)
#define NA   4096      // num agents / edges
#define FDIM 512
#define SDIM 6
#define HID  20
#define GDIM 2048      // 4*FDIM (LSTM gate width)
#define LWG  32        // WGs per LSTM role in the persistent pair kernel

__device__ __forceinline__ float sigf(float x) { return 1.0f / (1.0f + __expf(-x)); }
__device__ __forceinline__ float tanh_fast(float x) {
    float e = __expf(2.0f * x);
    return 1.0f - 2.0f / (e + 1.0f);
}

__device__ __forceinline__ void atomicMaxF(float* addr, float v) {
    if (v >= 0.0f) atomicMax((int*)addr, __float_as_int(v));
    else           atomicMin((unsigned int*)addr, __float_as_uint(v));
}

// ---------------------------------------------------------------------------
// phi MLP, fused per edge: msg = [xin[src] | states[src]-states[dst]] (518)
// 256 threads; w0 matmul K-split 12-way per column, LDS reduce.
// ---------------------------------------------------------------------------
__global__ void __launch_bounds__(256)
phi_fused(const float* __restrict__ xin, const float* __restrict__ states,
          const int* __restrict__ src, const int* __restrict__ dst,
          const float* __restrict__ w0, const float* __restrict__ b0,
          const float* __restrict__ w1, const float* __restrict__ b1,
          const float* __restrict__ w2, const float* __restrict__ b2,
          float* __restrict__ phi)
{
    int e = blockIdx.x, tid = threadIdx.x;
    __shared__ float msgv[FDIM + SDIM];
    __shared__ float red[240];
    __shared__ float hb1[HID];
    __shared__ float hb2[HID];
    int s = src[e], d = dst[e];
    for (int i = tid; i < FDIM; i += 256) msgv[i] = xin[(size_t)s * FDIM + i];
    if (tid < SDIM) msgv[FDIM + tid] = states[s * SDIM + tid] - states[d * SDIM + tid];
    __syncthreads();
    if (tid < 240) {
        int col = tid / 12, sg = tid % 12;
        int k0 = sg * 44, k1 = min(FDIM + SDIM, k0 + 44);
        float acc = 0.0f;
        for (int k = k0; k < k1; k++) acc += msgv[k] * w0[k * HID + col];
        red[tid] = acc;
    }
    __syncthreads();
    if (tid < HID) {
        float a = b0[tid];
#pragma unroll
        for (int q = 0; q < 12; q++) a += red[tid * 12 + q];
        hb1[tid] = fmaxf(a, 0.0f);
    }
    __syncthreads();
    if (tid < HID) {
        float a = b1[tid];
#pragma unroll
        for (int k = 0; k < HID; k++) a += hb1[k] * w1[k * HID + tid];
        hb2[tid] = fmaxf(a, 0.0f);
    }
    __syncthreads();
    for (int c = tid; c < FDIM; c += 256) {
        float a = b2[c];
#pragma unroll
        for (int k = 0; k < HID; k++) a += hb2[k] * w2[k * FDIM + c];
        phi[(size_t)e * FDIM + c] = a;
    }
}

// ---------------------------------------------------------------------------
// fp32 tiled GEMM: C[M,N] = A[M,K] @ B[K,N] + bias[N]; A split at col splitA.
// 128x128 tile, 256 threads, 8x8 microtile (2x2 blocks of 4x4 at +-64).
// blockIdx.z selects among up to 4 (B, bias, C) triples sharing the same A.
// ---------------------------------------------------------------------------
struct Ptrs4 {
    const float* B[4];
    const float* bias[4];
    float* C[4];
};

__global__ void __launch_bounds__(256)
gemm128(const float* __restrict__ A1, int lda1,
        const float* __restrict__ A2, int lda2, int splitA,
        Ptrs4 p, int M, int N, int K)
{
    __shared__ float a_lds[16][132];
    __shared__ float b_lds[16][132];
    const float* __restrict__ B    = p.B[blockIdx.z];
    const float* __restrict__ bias = p.bias[blockIdx.z];
    float* __restrict__ C          = p.C[blockIdx.z];
    const int tid = threadIdx.x;
    const int m0 = blockIdx.y * 128, n0 = blockIdx.x * 128;
    const int ar = tid >> 2, ak4 = (tid & 3) * 4;     // A loader: rows ar, ar+64
    const int br = tid >> 5, bc4 = (tid & 31) * 4;    // B loader: rows br, br+8
    const int ty = tid >> 4, tx = tid & 15;           // compute coords
    float acc[8][8] = {};

    for (int kt = 0; kt < K; kt += 16) {
        // ---- stage A (transposed) ----
        int ak = kt + ak4;
        const float* abase;
        int acol;
        if (ak < splitA) { abase = A1; acol = ak;          // lda1
            const float* r0 = abase + (size_t)(m0 + ar) * lda1 + acol;
            const float* r1 = abase + (size_t)(m0 + ar + 64) * lda1 + acol;
            float4 a0 = *(const float4*)r0;
            float4 a1 = *(const float4*)r1;
            a_lds[ak4 + 0][ar] = a0.x; a_lds[ak4 + 1][ar] = a0.y;
            a_lds[ak4 + 2][ar] = a0.z; a_lds[ak4 + 3][ar] = a0.w;
            a_lds[ak4 + 0][ar + 64] = a1.x; a_lds[ak4 + 1][ar + 64] = a1.y;
            a_lds[ak4 + 2][ar + 64] = a1.z; a_lds[ak4 + 3][ar + 64] = a1.w;
        } else {
            acol = ak - splitA;
            const float* r0 = A2 + (size_t)(m0 + ar) * lda2 + acol;
            const float* r1 = A2 + (size_t)(m0 + ar + 64) * lda2 + acol;
            float4 a0 = *(const float4*)r0;
            float4 a1 = *(const float4*)r1;
            a_lds[ak4 + 0][ar] = a0.x; a_lds[ak4 + 1][ar] = a0.y;
            a_lds[ak4 + 2][ar] = a0.z; a_lds[ak4 + 3][ar] = a0.w;
            a_lds[ak4 + 0][ar + 64] = a1.x; a_lds[ak4 + 1][ar + 64] = a1.y;
            a_lds[ak4 + 2][ar + 64] = a1.z; a_lds[ak4 + 3][ar + 64] = a1.w;
        }
        // ---- stage B ----
        {
            float4 b0v = *(const float4*)(B + (size_t)(kt + br) * N + n0 + bc4);
            float4 b1v = *(const float4*)(B + (size_t)(kt + br + 8) * N + n0 + bc4);
            *(float4*)&b_lds[br][bc4] = b0v;
            *(float4*)&b_lds[br + 8][bc4] = b1v;
        }
        __syncthreads();
#pragma unroll
        for (int kk = 0; kk < 16; kk++) {
            float av[8], bv[8];
            *(float4*)&av[0] = *(const float4*)&a_lds[kk][ty * 4];
            *(float4*)&av[4] = *(const float4*)&a_lds[kk][64 + ty * 4];
            *(float4*)&bv[0] = *(const float4*)&b_lds[kk][tx * 4];
            *(float4*)&bv[4] = *(const float4*)&b_lds[kk][64 + tx * 4];
#pragma unroll
            for (int i = 0; i < 8; i++)
#pragma unroll
                for (int j = 0; j < 8; j++)
                    acc[i][j] += av[i] * bv[j];
        }
        __syncthreads();
    }

    float4 bb0 = *(const float4*)(bias + n0 + tx * 4);
    float4 bb1 = *(const float4*)(bias + n0 + 64 + tx * 4);
    const float bbs0[4] = { bb0.x, bb0.y, bb0.z, bb0.w };
    const float bbs1[4] = { bb1.x, bb1.y, bb1.z, bb1.w };
#pragma unroll
    for (int i = 0; i < 8; i++) {
        int row = m0 + ((i < 4) ? (ty * 4 + i) : (64 + ty * 4 + i - 4));
        float4 o0, o1;
        o0.x = acc[i][0] + bbs0[0]; o0.y = acc[i][1] + bbs0[1];
        o0.z = acc[i][2] + bbs0[2]; o0.w = acc[i][3] + bbs0[3];
        o1.x = acc[i][4] + bbs1[0]; o1.y = acc[i][5] + bbs1[1];
        o1.z = acc[i][6] + bbs1[2]; o1.w = acc[i][7] + bbs1[3];
        *(float4*)&C[(size_t)row * N + n0 + tx * 4] = o0;
        *(float4*)&C[(size_t)row * N + n0 + 64 + tx * 4] = o1;
    }
}

// ---------------------------------------------------------------------------
// attention (generic segment softmax; with dst=arange it is singleton/exact)
// ---------------------------------------------------------------------------
__global__ void att_init(float* __restrict__ m, float* __restrict__ ssum)
{
    int i = blockIdx.x * blockDim.x + threadIdx.x;
    if (i < NA) { m[i] = -INFINITY; ssum[i] = 0.0f; }
}

__global__ void att_logits(const float* __restrict__ q, const float* __restrict__ k,
                           const int* __restrict__ src, const int* __restrict__ dst,
                           float* __restrict__ logits, float* __restrict__ m)
{
    int e = blockIdx.x, tid = threadIdx.x;
    int s = src[e], d = dst[e];
    const float4* qr = (const float4*)(q + (size_t)d * FDIM);
    const float4* kr = (const float4*)(k + (size_t)s * FDIM);
    float acc = 0.0f;
    for (int i = tid; i < FDIM / 4; i += 64) {
        float4 a = qr[i], b = kr[i];
        acc += a.x * b.x + a.y * b.y + a.z * b.z + a.w * b.w;
    }
    for (int off = 32; off; off >>= 1) acc += __shfl_down(acc, off);
    if (tid == 0) {
        float v = acc * 0.04419417382415922f;   // 1/sqrt(512)
        logits[e] = v;
        atomicMaxF(&m[d], v);
    }
}

__global__ void att_expsum(const float* __restrict__ logits, const float* __restrict__ m,
                           const int* __restrict__ dst,
                           float* __restrict__ ebuf, float* __restrict__ ssum)
{
    int e = blockIdx.x * blockDim.x + threadIdx.x;
    if (e < NA) {
        float v = __expf(logits[e] - m[dst[e]]);
        ebuf[e] = v;
        atomicAdd(&ssum[dst[e]], v);
    }
}

__global__ void att_scatter(const float* __restrict__ v, const int* __restrict__ src,
                            const int* __restrict__ dst, const float* __restrict__ ebuf,
                            const float* __restrict__ ssum, float* __restrict__ aggr)
{
    int e = blockIdx.x, tid = threadIdx.x;
    int s = src[e], d = dst[e];
    float alpha = ebuf[e] / ssum[d];
    const float* vr = v + (size_t)s * FDIM;
    float* ar = aggr + (size_t)d * FDIM;
    for (int c = tid; c < FDIM; c += 256) atomicAdd(&ar[c], alpha * vr[c]);
}

// ---------------------------------------------------------------------------
// Pipelined 2-layer LSTM scan. 64 WGs x 512 threads. (unchanged from R2)
// ---------------------------------------------------------------------------
__global__ void __launch_bounds__(512, 2)
lstm_pair(const float* __restrict__ pre0, const float* __restrict__ whh0,
          const float* __restrict__ wih1, const float* __restrict__ whh1,
          const float* __restrict__ b1,
          float* __restrict__ xout,
          unsigned long long* __restrict__ hfull,
          unsigned long long* __restrict__ hbuf1,
          unsigned int tag0, unsigned int tag1, int T)
{
    const int wg = blockIdx.x;
    const bool roleB = wg >= LWG;
    const int w = wg & (LWG - 1);
    const int tid = threadIdx.x;
    const int dl = tid & 15;
    const int gate = (tid >> 4) & 3;
    const int seg = tid >> 6;                // 0..7
    const int j = gate * 512 + w * 16 + dl;  // gate column

    float wreg[128];
    if (!roleB) {
        const float* wc = whh0 + (size_t)(seg * 64) * GDIM + j;
#pragma unroll
        for (int kk = 0; kk < 64; kk++) wreg[kk] = wc[(size_t)kk * GDIM];
    } else {
        const float* wc = (seg < 4)
            ? (wih1 + (size_t)(seg * 128) * GDIM + j)
            : (whh1 + (size_t)((seg - 4) * 128) * GDIM + j);
#pragma unroll
        for (int kk = 0; kk < 128; kk++) wreg[kk] = wc[(size_t)kk * GDIM];
    }

    __shared__ float h_lds[1024];   // A: [0:512]=h0(t-1). B: [0:512]=h0(t), [512:1024]=h1(t-1)
    __shared__ float red[512];
    __shared__ float gbuf[64];
    float c = 0.0f;
    float extra = 0.0f;             // A: pre0 row prefetch; B: bias
    if (tid < 64) extra = roleB ? b1[j] : pre0[j];
    if (!roleB) h_lds[tid] = 0.0f;
    else        h_lds[512 + tid] = 0.0f;
    __syncthreads();

    if (!roleB) {
        for (int t = 0; t < T; t++) {
            const float* hseg = h_lds + seg * 64;
            float a0 = 0, a1 = 0, a2 = 0, a3 = 0;
#pragma unroll
            for (int kk = 0; kk < 64; kk += 4) {
                float4 hv = *(const float4*)(hseg + kk);
                a0 += wreg[kk + 0] * hv.x;
                a1 += wreg[kk + 1] * hv.y;
                a2 += wreg[kk + 2] * hv.z;
                a3 += wreg[kk + 3] * hv.w;
            }
            red[tid] = (a0 + a1) + (a2 + a3);
            __syncthreads();
            if (tid < 64) {
                float tot = extra;
#pragma unroll
                for (int s = 0; s < 8; s++) tot += red[tid + 64 * s];
                gbuf[tid] = tot;
                if (t + 1 < T) extra = pre0[(size_t)(t + 1) * GDIM + j];  // prefetch
            }
            __syncthreads();
            if (tid < 16) {
                float ii = gbuf[tid], ff = gbuf[16 + tid], gg = gbuf[32 + tid], oo = gbuf[48 + tid];
                c = sigf(ff) * c + sigf(ii) * tanh_fast(gg);
                float h = sigf(oo) * tanh_fast(c);
                unsigned long long word =
                    ((unsigned long long)(tag0 + (unsigned)t + 1u) << 32) |
                    (unsigned long long)__float_as_uint(h);
                __hip_atomic_store(&hfull[(size_t)t * 512 + w * 16 + tid], word,
                                   __ATOMIC_RELAXED, __HIP_MEMORY_SCOPE_AGENT);
            }
            if (t + 1 < T) {
                unsigned long long want = tag0 + (unsigned)t + 1u;
                const unsigned long long* p = &hfull[(size_t)t * 512 + tid];
                unsigned long long v = __hip_atomic_load(p, __ATOMIC_RELAXED, __HIP_MEMORY_SCOPE_AGENT);
                while ((v >> 32) != want)
                    v = __hip_atomic_load(p, __ATOMIC_RELAXED, __HIP_MEMORY_SCOPE_AGENT);
                h_lds[tid] = __uint_as_float((unsigned)v);
                __syncthreads();
            }
        }
    } else {
        for (int t = 0; t < T; t++) {
            {   // poll h0(t)
                unsigned long long want = tag0 + (unsigned)t + 1u;
                const unsigned long long* p = &hfull[(size_t)t * 512 + tid];
                unsigned long long v = __hip_atomic_load(p, __ATOMIC_RELAXED, __HIP_MEMORY_SCOPE_AGENT);
                while ((v >> 32) != want)
                    v = __hip_atomic_load(p, __ATOMIC_RELAXED, __HIP_MEMORY_SCOPE_AGENT);
                h_lds[tid] = __uint_as_float((unsigned)v);
            }
            __syncthreads();
            const float* hseg = h_lds + seg * 128;   // covers [h0 ; h1] concat
            float a0 = 0, a1 = 0, a2 = 0, a3 = 0;
#pragma unroll
            for (int kk = 0; kk < 128; kk += 4) {
                float4 hv = *(const float4*)(hseg + kk);
                a0 += wreg[kk + 0] * hv.x;
                a1 += wreg[kk + 1] * hv.y;
                a2 += wreg[kk + 2] * hv.z;
                a3 += wreg[kk + 3] * hv.w;
            }
            red[tid] = (a0 + a1) + (a2 + a3);
            __syncthreads();
            if (tid < 64) {
                float tot = extra;   // bias b1[j]
#pragma unroll
                for (int s = 0; s < 8; s++) tot += red[tid + 64 * s];
                gbuf[tid] = tot;
            }
            __syncthreads();
            if (tid < 16) {
                float ii = gbuf[tid], ff = gbuf[16 + tid], gg = gbuf[32 + tid], oo = gbuf[48 + tid];
                c = sigf(ff) * c + sigf(ii) * tanh_fast(gg);
                float h = sigf(oo) * tanh_fast(c);
                xout[(size_t)t * 512 + w * 16 + tid] = h;
                unsigned long long word =
                    ((unsigned long long)(tag1 + (unsigned)t + 1u) << 32) |
                    (unsigned long long)__float_as_uint(h);
                __hip_atomic_store(&hbuf1[(t & 1) * 512 + w * 16 + tid], word,
                                   __ATOMIC_RELAXED, __HIP_MEMORY_SCOPE_AGENT);
            }
            if (t + 1 < T) {
                unsigned long long want = tag1 + (unsigned)t + 1u;
                const unsigned long long* p = &hbuf1[(t & 1) * 512 + tid];
                unsigned long long v = __hip_atomic_load(p, __ATOMIC_RELAXED, __HIP_MEMORY_SCOPE_AGENT);
                while ((v >> 32) != want)
                    v = __hip_atomic_load(p, __ATOMIC_RELAXED, __HIP_MEMORY_SCOPE_AGENT);
                h_lds[512 + tid] = __uint_as_float((unsigned)v);
                __syncthreads();
            }
        }
    }
}

// ---------------------------------------------------------------------------
__global__ void relu_ip(float* __restrict__ x, int n)
{
    int i = blockIdx.x * blockDim.x + threadIdx.x;
    if (i < n) x[i] = fmaxf(x[i], 0.0f);
}

__global__ void cbf_head(const float* __restrict__ xc, const float* __restrict__ w,
                         const float* __restrict__ b, float* __restrict__ out)
{
    int i = blockIdx.x, tid = threadIdx.x;
    const float* xr = xc + (size_t)i * FDIM;
    float acc = 0.0f;
    for (int d = tid; d < FDIM; d += 64) acc += fmaxf(xr[d], 0.0f) * w[d];
    for (int off = 32; off; off >>= 1) acc += __shfl_down(acc, off);
    if (tid == 0) out[i] = acc + b[0];
}

__global__ void zero_u64(unsigned long long* __restrict__ p, int n)
{
    int i = blockIdx.x * blockDim.x + threadIdx.x;
    int stride = gridDim.x * blockDim.x;
    for (; i < n; i += stride) p[i] = 0ull;
}

// ---------------------------------------------------------------------------
extern "C" void kernel_launch(void* const* d_in, const int* in_sizes, int n_in,
                              void* d_out, int out_size, void* d_ws, size_t ws_size,
                              hipStream_t stream)
{
    const float* x      = (const float*)d_in[0];
    const float* states = (const float*)d_in[1];
    const int*   src    = (const int*)d_in[2];
    const int*   dst    = (const int*)d_in[3];
    const float* phi_w0 = (const float*)d_in[4];
    const float* phi_b0 = (const float*)d_in[5];
    const float* phi_w1 = (const float*)d_in[6];
    const float* phi_b1 = (const float*)d_in[7];
    const float* phi_w2 = (const float*)d_in[8];
    const float* phi_b2 = (const float*)d_in[9];
    const float* tq_w = (const float*)d_in[10]; const float* tq_b = (const float*)d_in[11];
    const float* tk_w = (const float*)d_in[12]; const float* tk_b = (const float*)d_in[13];
    const float* tv_w = (const float*)d_in[14]; const float* tv_b = (const float*)d_in[15];
    const float* ts_w = (const float*)d_in[16]; const float* ts_b = (const float*)d_in[17];
    const float* wih0 = (const float*)d_in[18]; const float* whh0 = (const float*)d_in[19];
    const float* b0   = (const float*)d_in[20];
    const float* wih1 = (const float*)d_in[21]; const float* whh1 = (const float*)d_in[22];
    const float* b1   = (const float*)d_in[23];
    const float* cbf_w = (const float*)d_in[24]; const float* cbf_b = (const float*)d_in[25];

    float* ws = (float*)d_ws;
    size_t off = 0;
    auto alloc = [&](size_t n) { float* p = ws + off; off += n; return p; };
    float* xA     = alloc((size_t)NA * FDIM);
    float* xB     = alloc((size_t)NA * FDIM);
    float* phi    = alloc((size_t)NA * FDIM);
    float* qb     = alloc((size_t)NA * FDIM);
    float* kb     = alloc((size_t)NA * FDIM);
    float* vb     = alloc((size_t)NA * FDIM);
    float* aggr   = alloc((size_t)NA * FDIM);
    float* pre    = alloc((size_t)NA * GDIM);
    float* logits = alloc(NA);
    float* mb     = alloc(NA);
    float* ssum   = alloc(NA);
    float* ebuf   = alloc(NA);
    const int HFULL_WORDS = NA * 512;       // 2,097,152 u64
    unsigned long long* hfull = (unsigned long long*)alloc((size_t)2 * (HFULL_WORDS + 1024));
    unsigned long long* hbuf1 = hfull + HFULL_WORDS;

    float* out_x   = (float*)d_out;
    float* out_cbf = out_x + (size_t)NA * FDIM;

    zero_u64<<<2048, 256, 0, stream>>>(hfull, HFULL_WORDS + 1024);

    const float* xin = x;
    for (int l = 0; l < 4; l++) {
        float* xout = (l == 3) ? out_x : ((l & 1) ? xB : xA);

        phi_fused<<<NA, 256, 0, stream>>>(xin, states, src, dst,
            phi_w0 + (size_t)l * 518 * HID, phi_b0 + l * HID,
            phi_w1 + (size_t)l * HID * HID, phi_b1 + l * HID,
            phi_w2 + (size_t)l * HID * FDIM, phi_b2 + l * FDIM, phi);

        // fused Q/K/V/S: one dispatch, blockIdx.z picks weights/bias/output
        {
            Ptrs4 p;
            p.B[0] = tq_w + (size_t)l * FDIM * FDIM; p.bias[0] = tq_b + l * FDIM; p.C[0] = qb;
            p.B[1] = tk_w + (size_t)l * FDIM * FDIM; p.bias[1] = tk_b + l * FDIM; p.C[1] = kb;
            p.B[2] = tv_w + (size_t)l * FDIM * FDIM; p.bias[2] = tv_b + l * FDIM; p.C[2] = vb;
            p.B[3] = ts_w + (size_t)l * FDIM * FDIM; p.bias[3] = ts_b + l * FDIM; p.C[3] = aggr;
            gemm128<<<dim3(FDIM / 128, NA / 128, 4), 256, 0, stream>>>(
                phi, FDIM, phi, FDIM, FDIM, p, NA, FDIM, FDIM);
        }

        att_init<<<NA / 256, 256, 0, stream>>>(mb, ssum);
        att_logits<<<NA, 64, 0, stream>>>(qb, kb, src, dst, logits, mb);
        att_expsum<<<NA / 256, 256, 0, stream>>>(logits, mb, dst, ebuf, ssum);
        att_scatter<<<NA, 256, 0, stream>>>(vb, src, dst, ebuf, ssum, aggr);

        // pre0 = [aggr | xin] @ wih0 + b0
        {
            Ptrs4 p;
            p.B[0] = wih0 + (size_t)l * 1024 * GDIM; p.bias[0] = b0 + (size_t)l * GDIM; p.C[0] = pre;
            p.B[1] = p.B[0]; p.bias[1] = p.bias[0]; p.C[1] = pre;
            p.B[2] = p.B[0]; p.bias[2] = p.bias[0]; p.C[2] = pre;
            p.B[3] = p.B[0]; p.bias[3] = p.bias[0]; p.C[3] = pre;
            gemm128<<<dim3(GDIM / 128, NA / 128, 1), 256, 0, stream>>>(
                aggr, FDIM, xin, FDIM, FDIM, p, NA, GDIM, 1024);
        }

        // fused, pipelined LSTM0+LSTM1 (pre1 GEMM folded into role B)
        lstm_pair<<<2 * LWG, 512, 0, stream>>>(pre,
            whh0 + (size_t)l * FDIM * GDIM,
            wih1 + (size_t)l * FDIM * GDIM,
            whh1 + (size_t)l * FDIM * GDIM,
            b1 + (size_t)l * GDIM,
            xout, hfull, hbuf1,
            (unsigned)(2 * l) * NA, (unsigned)(2 * l + 1) * NA, NA);

        if (l == 0 || l == 2)
            relu_ip<<<(NA * FDIM + 255) / 256, 256, 0, stream>>>(xout, NA * FDIM);
        xin = xout;
    }

    cbf_head<<<NA, 64, 0, stream>>>(out_x, cbf_w, cbf_b, out_cbf);
}